// Round 3
// baseline (2276.737 us; speedup 1.0000x reference)
//
#include <hip/hip_runtime.h>
#include <math.h>

#define THREADS 256
constexpr int BATCH = 16;

// ---------------------------------------------------------------------------
// Workspace layout (floats):
//   K0t [125][23]        : 2875      K1t [20][125][23] : 57500
//   K2t [20][125][20]    : 50000
//   A0  [16][20][33^3]   : 11,499,840   (P2 aliases this region after combine)
//   A1  [16][20][18^3]   : 1,866,240
//   P1  [G1][16][23][18^3]  (tier A: G1=5 -> 10,730,880 fl; total 96.8 MB)
// ---------------------------------------------------------------------------

__global__ void synth_kernel(const float* __restrict__ W0,
                             const float* __restrict__ W1,
                             const float* __restrict__ W2,
                             float* __restrict__ K0,
                             float* __restrict__ K1,
                             float* __restrict__ K2) {
  __shared__ float Bsh[3][128];
  __shared__ float nrm[3];
  const int t = threadIdx.x;
  if (t < 125) {
    float dz = (float)(t / 25) - 2.0f;
    float dy = (float)((t / 5) % 5) - 2.0f;
    float dx = (float)(t % 5) - 2.0f;
    float r = sqrtf(dx * dx + dy * dy + dz * dz);
    for (int j = 0; j < 3; ++j) {
      float d = (r - (float)j) * (1.0f / 0.6f);
      Bsh[j][t] = expf(-0.5f * d * d);
    }
  }
  __syncthreads();
  if (t < 3) {
    float s = 0.f;
    for (int k = 0; k < 125; ++k) s += Bsh[t][k] * Bsh[t][k];
    nrm[t] = rsqrtf(s);
  }
  __syncthreads();
  if (t < 125) {
    for (int j = 0; j < 3; ++j) Bsh[j][t] *= nrm[j];
  }
  __syncthreads();
  for (int i = t; i < 125 * 23; i += blockDim.x) {
    int k = i / 23, oc = i % 23;
    const float* w = W0 + oc * 3;
    K0[i] = w[0] * Bsh[0][k] + w[1] * Bsh[1][k] + w[2] * Bsh[2][k];
  }
  for (int i = t; i < 20 * 125 * 23; i += blockDim.x) {
    int oc = i % 23, k = (i / 23) % 125, ic = i / (23 * 125);
    const float* w = W1 + (oc * 20 + ic) * 3;
    K1[i] = w[0] * Bsh[0][k] + w[1] * Bsh[1][k] + w[2] * Bsh[2][k];
  }
  for (int i = t; i < 20 * 125 * 20; i += blockDim.x) {
    int oc = i % 20, k = (i / 20) % 125, ic = i / (20 * 125);
    const float* w = W2 + (oc * 20 + ic) * 3;
    K2[i] = w[0] * Bsh[0][k] + w[1] * Bsh[1][k] + w[2] * Bsh[2][k];
  }
}

// Direct conv, stride 2, pad 3, 5^3 taps. Each thread computes an NX-strip of
// x-consecutive output voxels for ALL OC channels of one ic-group. Weights for
// the current input channel staged in LDS, read as broadcast float4 (b128) —
// each weight register feeds NX FMAs; stride-2 x-overlap reuses input loads.
// EPI: 0 = partials [g][b][OC][vox], 1 = gated (G==1, OC==23), 2 = plain (G==1).
template <int ICTOT, int ICG, int OC, int DIN, int DOUT, int NX, int EPI>
__global__ __launch_bounds__(THREADS)
void conv_kernel(const float* __restrict__ in, const float* __restrict__ K,
                 float* __restrict__ out) {
  constexpr int NVOX = DOUT * DOUT * DOUT;
  constexpr int G = ICTOT / ICG;
  constexpr int DIN3 = DIN * DIN * DIN;
  constexpr int XS = (DOUT + NX - 1) / NX;   // strips per x-row
  constexpr int SPI = DOUT * DOUT * XS;      // strips per (b,g)
  constexpr int NB = (SPI + THREADS - 1) / THREADS;
  constexpr int OCP = (OC + 3) & ~3;
  constexpr int NV = 2 * NX + 3;

  __shared__ __align__(16) float wsh[125 * OCP];

  const int bid = blockIdx.x;
  const int chunk = bid % NB;
  const int gb = bid / NB;
  const int g = gb % G;
  const int b = gb / G;
  const int t = threadIdx.x;
  const int s = chunk * THREADS + t;
  const bool active = s < SPI;
  const int si = active ? s : 0;
  const int zo = si / (DOUT * XS);
  const int yo = (si / XS) % DOUT;
  const int xo0 = (si % XS) * NX;

  float acc[OC][NX];
#pragma unroll
  for (int oc = 0; oc < OC; ++oc)
#pragma unroll
    for (int n = 0; n < NX; ++n) acc[oc][n] = 0.f;

  const float* __restrict__ ip0 = in + (size_t)(b * ICTOT + g * ICG) * DIN3;
  const float* __restrict__ wp0 = K + (size_t)(g * ICG) * 125 * OC;

  int xic[NV];
  bool xok[NV];
#pragma unroll
  for (int p = 0; p < NV; ++p) {
    int xi = 2 * xo0 - 3 + p;
    xok[p] = (unsigned)xi < (unsigned)DIN;
    xic[p] = min(max(xi, 0), DIN - 1);
  }

  for (int icl = 0; icl < ICG; ++icl) {
    __syncthreads();
    for (int i = t; i < 125 * OC; i += THREADS) {
      int tap = i / OC, oc = i % OC;
      wsh[tap * OCP + oc] = wp0[icl * 125 * OC + i];
    }
    __syncthreads();
    const float* __restrict__ ipc = ip0 + (size_t)icl * DIN3;
    for (int kz = 0; kz < 5; ++kz) {
      const int zi = 2 * zo - 3 + kz;
      const bool zok = (unsigned)zi < (unsigned)DIN;
      const int zic = min(max(zi, 0), DIN - 1);
      for (int ky = 0; ky < 5; ++ky) {
        const int yi = 2 * yo - 3 + ky;
        const bool yzok = zok && ((unsigned)yi < (unsigned)DIN);
        const int yic = min(max(yi, 0), DIN - 1);
        const float* __restrict__ row = ipc + ((size_t)zic * DIN + yic) * DIN;
        float v[NV];
#pragma unroll
        for (int p = 0; p < NV; ++p) {
          const float val = row[xic[p]];
          v[p] = (yzok && xok[p]) ? val : 0.f;
        }
        const int kb = ((kz * 5 + ky) * 5) * OCP;
#pragma unroll
        for (int kx = 0; kx < 5; ++kx) {
#pragma unroll
          for (int c4 = 0; c4 < OCP / 4; ++c4) {
            const float4 w4 = *(const float4*)&wsh[kb + kx * OCP + 4 * c4];
            const float wj[4] = {w4.x, w4.y, w4.z, w4.w};
#pragma unroll
            for (int j = 0; j < 4; ++j) {
              constexpr int base = 0;
              const int oc = c4 * 4 + j + base;
              if (oc < OC) {
#pragma unroll
                for (int n = 0; n < NX; ++n)
                  acc[oc][n] = fmaf(wj[j], v[2 * n + kx], acc[oc][n]);
              }
            }
          }
        }
      }
    }
  }

  if (!active) return;
  const int vbase = (zo * DOUT + yo) * DOUT + xo0;

  if constexpr (EPI == 1) {
    float* __restrict__ op = out + (size_t)b * 20 * NVOX + vbase;
#pragma unroll
    for (int n = 0; n < NX; ++n) {
      if (xo0 + n < DOUT) {
        const float g0 = 1.f / (1.f + expf(-acc[20][n]));
        const float g1 = 1.f / (1.f + expf(-acc[21][n]));
        const float g2 = 1.f / (1.f + expf(-acc[22][n]));
#pragma unroll
        for (int c = 0; c < 5; ++c) op[(size_t)c * NVOX + n] = fmaxf(acc[c][n], 0.f);
#pragma unroll
        for (int c = 0; c < 3; ++c) op[(size_t)(5 + c) * NVOX + n] = acc[5 + c][n] * g0;
#pragma unroll
        for (int c = 0; c < 5; ++c) op[(size_t)(8 + c) * NVOX + n] = acc[8 + c][n] * g1;
#pragma unroll
        for (int c = 0; c < 7; ++c) op[(size_t)(13 + c) * NVOX + n] = acc[13 + c][n] * g2;
      }
    }
  } else if constexpr (EPI == 0) {
    float* __restrict__ op = out + ((size_t)(g * BATCH + b) * OC) * NVOX + vbase;
#pragma unroll
    for (int oc = 0; oc < OC; ++oc)
#pragma unroll
      for (int n = 0; n < NX; ++n)
        if (xo0 + n < DOUT) op[(size_t)oc * NVOX + n] = acc[oc][n];
  } else {
    float* __restrict__ op = out + (size_t)b * OC * NVOX + vbase;
#pragma unroll
    for (int oc = 0; oc < OC; ++oc)
#pragma unroll
      for (int n = 0; n < NX; ++n)
        if (xo0 + n < DOUT) op[(size_t)oc * NVOX + n] = acc[oc][n];
  }
}

// Sum ic-group partials (23 ch) + gating -> 20 ch output.
template <int G, int NVOX>
__global__ __launch_bounds__(THREADS)
void combine_gate_kernel(const float* __restrict__ P, float* __restrict__ out) {
  const int tid = blockIdx.x * THREADS + threadIdx.x;
  if (tid >= BATCH * NVOX) return;
  const int vox = tid % NVOX;
  const int b = tid / NVOX;
  float s[23];
#pragma unroll
  for (int oc = 0; oc < 23; ++oc) s[oc] = 0.f;
  for (int g = 0; g < G; ++g) {
    const float* __restrict__ p = P + ((size_t)(g * BATCH + b) * 23) * NVOX + vox;
#pragma unroll
    for (int oc = 0; oc < 23; ++oc) s[oc] += p[(size_t)oc * NVOX];
  }
  const float g0 = 1.f / (1.f + expf(-s[20]));
  const float g1 = 1.f / (1.f + expf(-s[21]));
  const float g2 = 1.f / (1.f + expf(-s[22]));
  float* __restrict__ op = out + (size_t)b * 20 * NVOX + vox;
#pragma unroll
  for (int c = 0; c < 5; ++c) op[(size_t)c * NVOX] = fmaxf(s[c], 0.f);
#pragma unroll
  for (int c = 0; c < 3; ++c) op[(size_t)(5 + c) * NVOX] = s[5 + c] * g0;
#pragma unroll
  for (int c = 0; c < 5; ++c) op[(size_t)(8 + c) * NVOX] = s[8 + c] * g1;
#pragma unroll
  for (int c = 0; c < 7; ++c) op[(size_t)(13 + c) * NVOX] = s[13 + c] * g2;
}

// AvgSpacial over P2 partials [G][16][20][1000] + fc1(relu) + fc2.
template <int G>
__global__ __launch_bounds__(THREADS)
void head_kernel(const float* __restrict__ P2,
                 const float* __restrict__ fc1w, const float* __restrict__ fc1b,
                 const float* __restrict__ fc2w, const float* __restrict__ fc2b,
                 float* __restrict__ out) {
  const int b = blockIdx.x;
  const int t = threadIdx.x;
  __shared__ float part[200];
  __shared__ float xm[20];
  __shared__ float h[50];
  if (t < 200) {
    const int ch = t / 10, seg = t % 10;
    float s = 0.f;
    for (int g = 0; g < G; ++g) {
      const float* __restrict__ p = P2 + ((size_t)(g * BATCH + b) * 20 + ch) * 1000 + seg * 100;
      for (int i = 0; i < 100; ++i) s += p[i];
    }
    part[t] = s;
  }
  __syncthreads();
  if (t < 20) {
    float s = 0.f;
    for (int i = 0; i < 10; ++i) s += part[t * 10 + i];
    xm[t] = s * (1.0f / 1000.0f);
  }
  __syncthreads();
  if (t < 50) {
    float s = fc1b[t];
    for (int c = 0; c < 20; ++c) s += xm[c] * fc1w[t * 20 + c];
    h[t] = fmaxf(s, 0.f);
  }
  __syncthreads();
  if (t < 2) {
    float s = fc2b[t];
    for (int k = 0; k < 50; ++k) s += h[k] * fc2w[t * 50 + k];
    out[b * 2 + t] = s;
  }
}

extern "C" void kernel_launch(void* const* d_in, const int* in_sizes, int n_in,
                              void* d_out, int out_size, void* d_ws, size_t ws_size,
                              hipStream_t stream) {
  (void)in_sizes; (void)n_in; (void)out_size;
  const float* inp  = (const float*)d_in[0];
  const float* W0   = (const float*)d_in[1];
  const float* W1   = (const float*)d_in[2];
  const float* W2   = (const float*)d_in[3];
  const float* fc1w = (const float*)d_in[4];
  const float* fc1b = (const float*)d_in[5];
  const float* fc2w = (const float*)d_in[6];
  const float* fc2b = (const float*)d_in[7];
  float* out = (float*)d_out;

  float* ws = (float*)d_ws;
  float* K0 = ws;
  float* K1 = K0 + 2875;
  float* K2 = K1 + 57500;
  float* A0 = K2 + 50000;
  float* A1 = A0 + (size_t)11499840;
  float* P1 = A1 + (size_t)1866240;
  float* P2 = A0;  // A0 is dead after combine; conv2 partials alias it

  const size_t favail = ws_size / 4;
  const size_t fixed = 2875 + 57500 + 50000 + (size_t)11499840 + 1866240;  // 13,476,455

  hipLaunchKernelGGL(synth_kernel, dim3(1), dim3(256), 0, stream, W0, W1, W2, K0, K1, K2);

  // conv0: [16,1,64^3] -> gated -> A0 [16,20,33^3]. NX=3, XS=11, SPI=11979.
  hipLaunchKernelGGL((conv_kernel<1, 1, 23, 64, 33, 3, 1>), dim3(16 * 47), dim3(THREADS), 0,
                     stream, inp, K0, A0);

  if (favail >= fixed + (size_t)5 * BATCH * 23 * 5832) {
    // Tier A: conv1 ICG=4 x G=5. SPI=18*18*6=1944, NB=8.
    hipLaunchKernelGGL((conv_kernel<20, 4, 23, 33, 18, 3, 0>), dim3(16 * 5 * 8), dim3(THREADS), 0,
                       stream, A0, K1, P1);
    hipLaunchKernelGGL((combine_gate_kernel<5, 5832>), dim3((16 * 5832 + THREADS - 1) / THREADS),
                       dim3(THREADS), 0, stream, P1, A1);
    // conv2 ICG=1 x G=20, NX=2: SPI=10*10*5=500, NB=2.
    hipLaunchKernelGGL((conv_kernel<20, 1, 20, 18, 10, 2, 0>), dim3(16 * 20 * 2), dim3(THREADS), 0,
                       stream, A1, K2, P2);
    hipLaunchKernelGGL((head_kernel<20>), dim3(BATCH), dim3(THREADS), 0, stream, P2, fc1w, fc1b,
                       fc2w, fc2b, out);
  } else if (favail >= fixed + (size_t)4 * BATCH * 23 * 5832) {
    // Tier B: conv1 ICG=5 x G=4.
    hipLaunchKernelGGL((conv_kernel<20, 5, 23, 33, 18, 3, 0>), dim3(16 * 4 * 8), dim3(THREADS), 0,
                       stream, A0, K1, P1);
    hipLaunchKernelGGL((combine_gate_kernel<4, 5832>), dim3((16 * 5832 + THREADS - 1) / THREADS),
                       dim3(THREADS), 0, stream, P1, A1);
    hipLaunchKernelGGL((conv_kernel<20, 1, 20, 18, 10, 2, 0>), dim3(16 * 20 * 2), dim3(THREADS), 0,
                       stream, A1, K2, P2);
    hipLaunchKernelGGL((head_kernel<20>), dim3(BATCH), dim3(THREADS), 0, stream, P2, fc1w, fc1b,
                       fc2w, fc2b, out);
  } else {
    // Tier C: fused fallback, no partials. A2 goes where P1 would.
    float* A2 = P1;
    hipLaunchKernelGGL((conv_kernel<20, 20, 23, 33, 18, 3, 1>), dim3(16 * 8), dim3(THREADS), 0,
                       stream, A0, K1, A1);
    hipLaunchKernelGGL((conv_kernel<20, 20, 20, 18, 10, 2, 2>), dim3(16 * 2), dim3(THREADS), 0,
                       stream, A1, K2, A2);
    hipLaunchKernelGGL((head_kernel<1>), dim3(BATCH), dim3(THREADS), 0, stream, A2, fc1w, fc1b,
                       fc2w, fc2b, out);
  }
}